// Round 2
// baseline (328.750 us; speedup 1.0000x reference)
//
#include <hip/hip_runtime.h>

// Inverse-scatter map: slot[t] = j+1 if scatter_idx[j] == t (valid), else 0.
__global__ void build_slot_kernel(const int* __restrict__ scatter_idx,
                                  int* __restrict__ slot, int n, int T) {
    int j = blockIdx.x * blockDim.x + threadIdx.x;
    if (j < n) {
        int t = scatter_idx[j];
        if ((unsigned)t < (unsigned)T) slot[t] = j + 1;
    }
}

// One full token row per block (D=2048 floats = 512 float4; 256 threads x 2).
// slot/rpm loads are block-uniform broadcasts; branch is wave-uniform.
__global__ void moe_out_kernel(const float4* __restrict__ eo,
                               const float4* __restrict__ x,
                               const float* __restrict__ rpm,
                               const int* __restrict__ slot,
                               float4* __restrict__ out, int D4) {
    const int t = blockIdx.x;
    const size_t row = (size_t)t * D4;
    const int s = slot[t];
    const float4* __restrict__ src;
    float f;
    if (s > 0) {
        src = eo + (size_t)(s - 1) * D4;
        f = rpm[t];
    } else {
        src = x + row;
        f = 1.0f;
    }
    for (int c = threadIdx.x; c < D4; c += blockDim.x) {
        float4 v = src[c];
        v.x *= f; v.y *= f; v.z *= f; v.w *= f;
        out[row + c] = v;
    }
}

extern "C" void kernel_launch(void* const* d_in, const int* in_sizes, int n_in,
                              void* d_out, int out_size, void* d_ws, size_t ws_size,
                              hipStream_t stream) {
    const float* eo          = (const float*)d_in[0];  // (E*C, D) fp32
    const float* x           = (const float*)d_in[1];  // (B, S, D) fp32
    const float* rpm         = (const float*)d_in[2];  // (T,) fp32
    const int*   scatter_idx = (const int*)d_in[3];    // (E*C,) int32
    // d_in[4] (dropped_mask) unused: dropped == token absent from scatter_idx.

    const int T  = in_sizes[2];            // 16384 tokens
    const int D  = in_sizes[1] / T;        // 2048
    const int n  = in_sizes[3];            // E*C = 20480 slots
    const int D4 = D / 4;                  // 512 float4 per row

    int* slot = (int*)d_ws;                // T ints of scratch
    hipMemsetAsync(slot, 0, (size_t)T * sizeof(int), stream);

    build_slot_kernel<<<(n + 255) / 256, 256, 0, stream>>>(scatter_idx, slot, n, T);

    moe_out_kernel<<<T, 256, 0, stream>>>(
        (const float4*)eo, (const float4*)x, rpm, slot, (float4*)d_out, D4);
}